// Round 11
// baseline (1369.173 us; speedup 1.0000x reference)
//
#include <hip/hip_runtime.h>
#include <cstdint>
#include <cstddef>

#define NN 200000
#define NE 600000
#define NG 8192
#define C0 32
#define C1 128
#define C2 256
#define MLPH 256
#define NCLS 10
#define NB (3 * NN)
#define SCAN_BPB 1024
#define SCAN_NBLK ((NB + SCAN_BPB - 1) / SCAN_BPB)
#define NREP 8  // stats atomic replication

typedef __attribute__((ext_vector_type(8))) short short8b;  // 8 bf16 = 4 VGPR
typedef __attribute__((ext_vector_type(4))) float f32x4;

__device__ __forceinline__ void atomAddF(float* p, float v) { unsafeAtomicAdd(p, v); }

__device__ __forceinline__ float b2f(unsigned short u) {
  union { unsigned u; float f; } v; v.u = ((unsigned)u) << 16; return v.f;
}
__device__ __forceinline__ unsigned short f2b(float f) {  // RNE
  union { float f; unsigned u; } v; v.f = f;
  return (unsigned short)((v.u + 0x7FFF + ((v.u >> 16) & 1)) >> 16);
}

// ---------------- small utility kernels ----------------
__global__ __launch_bounds__(256) void k_fill(float* __restrict__ p, int n, float v) {
  int i = blockIdx.x * 256 + threadIdx.x;
  if (i < n) p[i] = v;
}

__global__ __launch_bounds__(256) void k_counts(const int* __restrict__ batch, float* __restrict__ counts) {
  int n = blockIdx.x * 256 + threadIdx.x;
  if (n < NN) atomAddF(&counts[batch[n]], 1.f);
}

// ---------------- CSR build: histogram (= degree), scan, place ----------------
__global__ __launch_bounds__(256) void k_hist(const int* __restrict__ dst, const int* __restrict__ et,
                                              int* __restrict__ cnt) {
  int e = blockIdx.x * 256 + threadIdx.x;
  if (e < NE) atomicAdd(&cnt[et[e] * NN + dst[e]], 1);
}

__global__ __launch_bounds__(256) void k_dinvI(const int* __restrict__ cnt, float* __restrict__ dinv) {
  int i = blockIdx.x * 256 + threadIdx.x;
  if (i < NB) { int c = cnt[i]; dinv[i] = (c > 0) ? 1.f / sqrtf((float)c) : 0.f; }
}

__global__ __launch_bounds__(256) void k_scan1(const int* __restrict__ cnt, int* __restrict__ starts,
                                               int* __restrict__ bsum) {
  __shared__ int sh[256];
  const int b0 = blockIdx.x * SCAN_BPB + threadIdx.x * 4;
  int v[4]; int tot = 0;
#pragma unroll
  for (int j = 0; j < 4; j++) {
    int b = b0 + j;
    v[j] = tot;
    tot += (b < NB) ? cnt[b] : 0;
  }
  sh[threadIdx.x] = tot;
  __syncthreads();
  for (int ofs = 1; ofs < 256; ofs <<= 1) {
    int add = (threadIdx.x >= ofs) ? sh[threadIdx.x - ofs] : 0;
    __syncthreads();
    sh[threadIdx.x] += add;
    __syncthreads();
  }
  const int excl = (threadIdx.x == 0) ? 0 : sh[threadIdx.x - 1];
#pragma unroll
  for (int j = 0; j < 4; j++) {
    int b = b0 + j;
    if (b < NB) starts[b] = excl + v[j];
  }
  if (threadIdx.x == 255) bsum[blockIdx.x] = sh[255];
}

__global__ void k_scan2(int* __restrict__ bsum) {
  if (threadIdx.x == 0) {
    int acc = 0;
    for (int i = 0; i < SCAN_NBLK; i++) { int t = bsum[i]; bsum[i] = acc; acc += t; }
  }
}

__global__ __launch_bounds__(256) void k_scan3(int* __restrict__ starts, const int* __restrict__ bsum) {
  int b = blockIdx.x * 256 + threadIdx.x;
  if (b < NB) starts[b] += bsum[b / SCAN_BPB];
}

// After k_place, starts[b] == end(b); list for bin b = [b ? starts[b-1] : 0, starts[b])
__global__ __launch_bounds__(256) void k_place(const int* __restrict__ src, const int* __restrict__ dst,
                                               const int* __restrict__ et, int* __restrict__ starts,
                                               int* __restrict__ esrc) {
  int e = blockIdx.x * 256 + threadIdx.x;
  if (e >= NE) return;
  int b = et[e] * NN + dst[e];
  int pos = atomicAdd(&starts[b], 1);
  esrc[pos] = src[e];
}

// ---------------- weight prep: fragment-ordered bf16 ----------------
// [m:4][p:COUT/64][kk:CIN/32][ct:4][l:64][j:8]; ki = kk*32+(l>>4)*4+(j&3)+16*(j>>2), c = p*64+ct*16+(l&15)
__global__ __launch_bounds__(256) void k_prepw(const float* __restrict__ Wid, const float* __restrict__ Wc,
                                               unsigned short* __restrict__ Wtf, int CIN_, int COUT_) {
  int i = blockIdx.x * 256 + threadIdx.x;
  if (i >= 4 * CIN_ * COUT_) return;
  int j = i & 7, lq = (i >> 3) & 63, ct = (i >> 9) & 3;
  int rest = i >> 11;
  int KK = CIN_ / 32, NP = COUT_ / 64;
  int kk = rest % KK; rest /= KK;
  int p = rest % NP; int m = rest / NP;
  int ki = kk * 32 + (lq >> 4) * 4 + (j & 3) + 16 * (j >> 2);
  int c = p * 64 + ct * 16 + (lq & 15);
  float wv = (m == 0) ? Wid[(size_t)ki * COUT_ + c] : Wc[(size_t)((m - 1) * CIN_ + ki) * COUT_ + c];
  Wtf[i] = f2b(wv);
}

// ---------------- gather-reduce aggregation (CSR), fragment-permuted layout ----------------
// Position layout: pos = kk*32 + lq*8 + j holds channel kk*32 + lq*4 + (j&3) + 16*(j>>2).
// Layer-2 h (out1) is ALREADY position-permuted -> oblivious. Layer-1 reads x at permuted channel.
template <int CIN, typename TIN>
__global__ __launch_bounds__(256) void k_agg(const int* __restrict__ starts, const int* __restrict__ esrc,
                                             const float* __restrict__ dinv, const TIN* __restrict__ h,
                                             unsigned short* __restrict__ aggXb, int lo, int nloc) {
  constexpr int TPB = (CIN == 32) ? 32 : 64;
  constexpr int V = CIN / TPB;  // 1 or 2
  const int idx = blockIdx.x * 256 + threadIdx.x;
  const int bl = idx / TPB;
  const int lane = idx % TPB;
  if (bl >= 3 * nloc) return;
  const int t = bl / nloc;
  const int bin = t * NN + lo + (bl - t * nloc);
  const int s = (bin == 0) ? 0 : starts[bin - 1];
  const int e2 = starts[bin];
  int readoff;
  if constexpr (CIN == 32) {
    readoff = ((lane >> 3) & 3) * 4 + (lane & 3) + 16 * ((lane >> 2) & 1);  // permuted channel
  } else {
    readoff = lane * V;  // position-oblivious
  }
  float acc[V];
#pragma unroll
  for (int j = 0; j < V; j++) acc[j] = 0.f;
  for (int i = s; i < e2; i++) {
    const int sn = esrc[i];
    const float dv = dinv[(size_t)t * NN + sn];
    if (dv == 0.f) continue;
    const TIN* hp = h + (size_t)sn * CIN + readoff;
#pragma unroll
    for (int j = 0; j < V; j++) {
      float v;
      if constexpr (sizeof(TIN) == 2) v = b2f(((const unsigned short*)hp)[j]);
      else v = ((const float*)hp)[j];
      acc[j] = fmaf(v, dv, acc[j]);
    }
  }
  const float dvd = dinv[bin];
  unsigned short* op = aggXb + (size_t)bl * CIN + lane * V;
#pragma unroll
  for (int j = 0; j < V; j++) op[j] = f2b(acc[j] * dvd);
}

// ---------------- fused finish: persistent, barrier-free after stage, m-pipelined ----------------
// 512 thr = 8 waves, supertile = 128 rows (wave w owns rows w*16..w*16+15).
// Weights (all 4 matrices, one 64-col panel) staged to LDS once. A-frags are ONE 16B load
// per (m,kk) thanks to the permuted layout; next-m frags prefetch during current-m MFMAs.
// Stats accumulate in registers across supertiles (one atomic flush per block).
#define LOADX(A, stv)                                                                           \
  {                                                                                             \
    const int row_ = (stv) * 128 + w * 16 + lr;                                                 \
    const bool v_ = row_ < nloc;                                                                \
    if constexpr (INBF16) {                                                                     \
      const short8b* xr_ =                                                                      \
          (const short8b*)((const unsigned short*)Xv + (size_t)(lo + row_) * CIN) + lq;         \
      _Pragma("unroll") for (int kk_ = 0; kk_ < KK; kk_++) A[kk_] = v_ ? xr_[kk_ * 4] : z8;     \
    } else {                                                                                    \
      const float* xr_ = (const float*)Xv + (size_t)(lo + row_) * CIN;                          \
      _Pragma("unroll") for (int kk_ = 0; kk_ < KK; kk_++) {                                    \
        float4 v0_ = v_ ? *(const float4*)(xr_ + kk_ * 32 + lq * 4) : make_float4(0, 0, 0, 0);  \
        float4 v1_ =                                                                            \
            v_ ? *(const float4*)(xr_ + kk_ * 32 + 16 + lq * 4) : make_float4(0, 0, 0, 0);      \
        union { ushort4 u4[2]; short8b v; } t_;                                                 \
        t_.u4[0] = make_ushort4(f2b(v0_.x), f2b(v0_.y), f2b(v0_.z), f2b(v0_.w));                \
        t_.u4[1] = make_ushort4(f2b(v1_.x), f2b(v1_.y), f2b(v1_.z), f2b(v1_.w));                \
        A[kk_] = t_.v;                                                                          \
      }                                                                                         \
    }                                                                                           \
  }

#define LOADA(A, stv, mm)                                                                       \
  {                                                                                             \
    const int row_ = (stv) * 128 + w * 16 + lr;                                                 \
    const bool v_ = row_ < nloc;                                                                \
    const short8b* ar_ =                                                                        \
        (const short8b*)(aggXb + ((size_t)((mm)-1) * nloc + row_) * CIN) + lq;                  \
    _Pragma("unroll") for (int kk_ = 0; kk_ < KK; kk_++) A[kk_] = v_ ? ar_[kk_ * 4] : z8;       \
  }

#define COMPM(A, mm)                                                                            \
  {                                                                                             \
    f32x4 acc_[4];                                                                              \
    _Pragma("unroll") for (int c_ = 0; c_ < 4; c_++) acc_[c_] = (f32x4){0.f, 0.f, 0.f, 0.f};    \
    _Pragma("unroll") for (int kk_ = 0; kk_ < KK; kk_++) {                                      \
      _Pragma("unroll") for (int c_ = 0; c_ < 4; c_++)                                          \
          acc_[c_] = __builtin_amdgcn_mfma_f32_16x16x32_bf16(                                   \
              A[kk_], wlds[((mm)*KK + kk_) * 256 + c_ * 64 + l], acc_[c_], 0, 0, 0);            \
    }                                                                                           \
    _Pragma("unroll") for (int c_ = 0; c_ < 4; c_++) {                                          \
      _Pragma("unroll") for (int j_ = 0; j_ < 4; j_++)                                          \
          run[c_][j_] += fmaxf(acc_[c_][j_] + bb[(mm)][c_], 0.f);                               \
    }                                                                                           \
  }

template <int CIN, int COUT, int SETS, bool INBF16, bool WRITEOUT, bool DOPOOL>
__global__ __launch_bounds__(512, 4) void k_fin(
    const void* __restrict__ Xv, const unsigned short* __restrict__ aggXb,
    int lo, int nloc, const unsigned short* __restrict__ Wtf,
    const float* __restrict__ bid, const float* __restrict__ bc,
    unsigned short* __restrict__ outb, float* __restrict__ stats,
    float* __restrict__ pooled, const int* __restrict__ batch) {
  constexpr int NP = COUT / 64;
  constexpr int KK = CIN / 32;
  constexpr int NFR = 4 * KK * 256;
  constexpr int WB = NFR * 16;
  constexpr int SB = WRITEOUT ? 8 * 16 * 68 * 4 : 0;
  __shared__ __align__(16) char smem[WB + SB + 16];
  short8b* wlds = (short8b*)smem;
  float* sstripB = (float*)(smem + WB);

  const int b = blockIdx.x;
  const int xcd = b & 7, q = b >> 3;
  const int p = q % NP, set = q / NP;
  const int c0 = p * 64;
  const int tid = threadIdx.x, w = tid >> 6, l = tid & 63, lr = l & 15, lq = l >> 4;

  for (int f = tid; f < NFR; f += 512) {
    int m = f / (KK * 256), r = f - m * (KK * 256);
    wlds[f] = ((const short8b*)Wtf)[(size_t)(m * NP + p) * (KK * 256) + r];
  }
  float bb[4][4];
#pragma unroll
  for (int m = 0; m < 4; m++) {
    const float* bp = (m == 0) ? bid : bc + (size_t)(m - 1) * COUT;
#pragma unroll
    for (int ct = 0; ct < 4; ct++) bb[m][ct] = bp[c0 + ct * 16 + lr];
  }
  __syncthreads();

  const int NT = (nloc + 127) >> 7;
  const int STEP = 8 * SETS;
  const short8b z8 = {0, 0, 0, 0, 0, 0, 0, 0};
  float sS[4] = {0.f, 0.f, 0.f, 0.f}, sSS[4] = {0.f, 0.f, 0.f, 0.f};

  short8b A0[KK], A1[KK];
  int st = xcd + 8 * set;
  if (st < NT) LOADX(A0, st);
  while (st < NT) {
    f32x4 run[4];
#pragma unroll
    for (int c_ = 0; c_ < 4; c_++) run[c_] = (f32x4){0.f, 0.f, 0.f, 0.f};
    LOADA(A1, st, 1);
    COMPM(A0, 0);
    LOADA(A0, st, 2);
    COMPM(A1, 1);
    LOADA(A1, st, 3);
    COMPM(A0, 2);
    {
      const int stn = st + STEP;
      if (stn < NT) LOADX(A0, stn);
    }
    COMPM(A1, 3);

    // ---- epilogue (no barriers) ----
    int rl = nloc - (st * 128 + w * 16);
    rl = rl < 0 ? 0 : (rl > 16 ? 16 : rl);
    if constexpr (WRITEOUT) {
      float* strip = sstripB + w * (16 * 68);
#pragma unroll
      for (int c_ = 0; c_ < 4; c_++)
#pragma unroll
        for (int j_ = 0; j_ < 4; j_++) strip[(lq * 4 + j_) * 68 + c_ * 16 + lr] = run[c_][j_];
      // write the wave's 16 rows x 64 PANEL positions (local pos pl = pg*8+j of panel p):
      // channel(pl) = c0 + (pg>>2)*32 + (pg&3)*4 + (j&3) + 16*(j>>2)  -> sp[j] / sp[16+(j&3)]
#pragma unroll
      for (int t_ = 0; t_ < 2; t_++) {
        const int task = t_ * 64 + l;  // 128 tasks = 16 rows x 8 pos-groups
        const int r_ = task >> 3, pg = task & 7;
        if (r_ < rl) {
          const float* sp = strip + r_ * 68 + (pg >> 2) * 32 + (pg & 3) * 4;
          union { ushort4 u4[2]; short8b v; } o_;
          o_.u4[0] = make_ushort4(f2b(sp[0]), f2b(sp[1]), f2b(sp[2]), f2b(sp[3]));
          o_.u4[1] = make_ushort4(f2b(sp[16]), f2b(sp[17]), f2b(sp[18]), f2b(sp[19]));
          *(short8b*)(outb + (size_t)(lo + st * 128 + w * 16 + r_) * COUT + c0 + pg * 8) = o_.v;
        }
      }
    }
#pragma unroll
    for (int j_ = 0; j_ < 4; j_++) {
      if (lq * 4 + j_ < rl) {
#pragma unroll
        for (int c_ = 0; c_ < 4; c_++) {
          float v_ = run[c_][j_];
          sS[c_] += v_;
          sSS[c_] += v_ * v_;
        }
      }
    }
    if constexpr (DOPOOL) {
      int bt[4];
      const int rb = lo + st * 128 + w * 16 + lq * 4;
      if (lq * 4 + 3 < rl) {
        int4 b4 = *(const int4*)&batch[rb];
        bt[0] = b4.x; bt[1] = b4.y; bt[2] = b4.z; bt[3] = b4.w;
      } else {
#pragma unroll
        for (int j_ = 0; j_ < 4; j_++) bt[j_] = (lq * 4 + j_ < rl) ? batch[rb + j_] : -1;
      }
      float pa0 = 0.f, pa1 = 0.f, pa2 = 0.f, pa3 = 0.f;
      int cur = -1;
#pragma unroll
      for (int j_ = 0; j_ < 4; j_++) {
        const int g_ = bt[j_];
        if (g_ != cur) {
          if (cur >= 0) {
            float* pp = pooled + (size_t)cur * C2 + c0 + lr;
            atomAddF(pp, pa0); atomAddF(pp + 16, pa1); atomAddF(pp + 32, pa2); atomAddF(pp + 48, pa3);
          }
          pa0 = pa1 = pa2 = pa3 = 0.f;
          cur = g_;
        }
        if (g_ >= 0) { pa0 += run[0][j_]; pa1 += run[1][j_]; pa2 += run[2][j_]; pa3 += run[3][j_]; }
      }
      if (cur >= 0) {
        float* pp = pooled + (size_t)cur * C2 + c0 + lr;
        atomAddF(pp, pa0); atomAddF(pp + 16, pa1); atomAddF(pp + 32, pa2); atomAddF(pp + 48, pa3);
      }
    }
    st += STEP;
  }

  // ---- one stats flush per block (reduce over lq lanes via shfl) ----
  float* srep = stats + (size_t)(b & (NREP - 1)) * 2 * COUT;
#pragma unroll
  for (int c_ = 0; c_ < 4; c_++) {
    float a = sS[c_];
    a += __shfl_xor(a, 16); a += __shfl_xor(a, 32);
    float s2 = sSS[c_];
    s2 += __shfl_xor(s2, 16); s2 += __shfl_xor(s2, 32);
    if (lq == 0) {
      atomAddF(&srep[c0 + c_ * 16 + lr], a);
      atomAddF(&srep[COUT + c0 + c_ * 16 + lr], s2);
    }
  }
}

// ---------------- BN finalize (sums NREP replicas) -> per-channel scale/shift ----------------
__global__ __launch_bounds__(256) void k_bnfin(const float* __restrict__ stats, const float* __restrict__ gamma,
                                               const float* __restrict__ beta, float* __restrict__ sc,
                                               float* __restrict__ sh, int COUT) {
  int c = threadIdx.x;
  if (c < COUT) {
    float su = 0.f, ssu = 0.f;
    for (int r = 0; r < NREP; r++) {
      su += stats[(size_t)r * 2 * COUT + c];
      ssu += stats[(size_t)r * 2 * COUT + COUT + c];
    }
    const float invN = 1.f / (float)NN;
    float m = su * invN;
    float v = ssu * invN - m * m;
    float s = gamma[c] / sqrtf(v + 1e-5f);
    sc[c] = s;
    sh[c] = fmaf(-m, s, beta[c]);
  }
}

// ---------------- fold BN1 into out1 (bf16, in place, position-permuted layout) ----------------
__global__ __launch_bounds__(256) void k_bnfold(unsigned short* __restrict__ o, const float* __restrict__ sc,
                                                const float* __restrict__ sh) {
  size_t i8 = ((size_t)blockIdx.x * 256 + threadIdx.x) * 8;
  if (i8 >= (size_t)NN * C1) return;
  const int posr = (int)(i8 & (C1 - 1));           // position of first elem in row (mult of 8)
  const int b2 = (posr & ~31) + ((posr >> 3) & 3) * 4;  // channel base: j<4 -> b2+j, j>=4 -> b2+16+(j&3)
  float4 scA = *(const float4*)&sc[b2], scB = *(const float4*)&sc[b2 + 16];
  float4 shA = *(const float4*)&sh[b2], shB = *(const float4*)&sh[b2 + 16];
  ushort4 a = *(ushort4*)(o + i8);
  ushort4 b = *(ushort4*)(o + i8 + 4);
  a.x = f2b(fmaf(b2f(a.x), scA.x, shA.x));
  a.y = f2b(fmaf(b2f(a.y), scA.y, shA.y));
  a.z = f2b(fmaf(b2f(a.z), scA.z, shA.z));
  a.w = f2b(fmaf(b2f(a.w), scA.w, shA.w));
  b.x = f2b(fmaf(b2f(b.x), scB.x, shB.x));
  b.y = f2b(fmaf(b2f(b.y), scB.y, shB.y));
  b.z = f2b(fmaf(b2f(b.z), scB.z, shB.z));
  b.w = f2b(fmaf(b2f(b.w), scB.w, shB.w));
  *(ushort4*)(o + i8) = a;
  *(ushort4*)(o + i8 + 4) = b;
}

// ---------------- MLP head: BN2 affine folded into pooled sums ----------------
__global__ __launch_bounds__(256) void k_mlp(const float* __restrict__ pooled, const float* __restrict__ counts,
                                             const float* __restrict__ sc2, const float* __restrict__ sh2,
                                             const float* __restrict__ Wf1, const float* __restrict__ bf1,
                                             const float* __restrict__ Wf2, const float* __restrict__ bf2,
                                             float* __restrict__ out) {
  __shared__ float feat[257];
  __shared__ float hid[256];
  const int g = blockIdx.x, t = threadIdx.x;
  const float cnt = counts[g];
  feat[t] = fmaf(sc2[t], pooled[(size_t)g * C2 + t], sh2[t] * cnt);
  if (t == 0) feat[256] = cnt * 0.025f;
  __syncthreads();
  float acc = bf1[t];
  for (int i = 0; i < 257; i++) acc = fmaf(feat[i], Wf1[(size_t)i * MLPH + t], acc);
  hid[t] = fmaxf(acc, 0.f);
  __syncthreads();
  if (t < NCLS) {
    float o = bf2[t];
    for (int j = 0; j < MLPH; j++) o = fmaf(hid[j], Wf2[(size_t)j * NCLS + t], o);
    out[(size_t)g * NCLS + t] = o;
  }
}

extern "C" void kernel_launch(void* const* d_in, const int* in_sizes, int n_in,
                              void* d_out, int out_size, void* d_ws, size_t ws_size,
                              hipStream_t stream) {
  const float* x = (const float*)d_in[0];
  const int* ei = (const int*)d_in[1];
  const int* et = (const int*)d_in[2];
  const int* batch = (const int*)d_in[3];
  const float* Wc0 = (const float*)d_in[4];
  const float* bc0 = (const float*)d_in[5];
  const float* Wid0 = (const float*)d_in[6];
  const float* bid0 = (const float*)d_in[7];
  const float* gm0 = (const float*)d_in[8];
  const float* bt0 = (const float*)d_in[9];
  const float* Wc1 = (const float*)d_in[10];
  const float* bc1 = (const float*)d_in[11];
  const float* Wid1 = (const float*)d_in[12];
  const float* bid1 = (const float*)d_in[13];
  const float* gm1 = (const float*)d_in[14];
  const float* bt1 = (const float*)d_in[15];
  const float* Wf1 = (const float*)d_in[16];
  const float* bf1 = (const float*)d_in[17];
  const float* Wf2 = (const float*)d_in[18];
  const float* bf2 = (const float*)d_in[19];
  const int* srcI = ei;
  const int* dstI = ei + NE;
  float* outp = (float*)d_out;

  char* ws = (char*)d_ws;
  size_t off = 0;
  auto take = [&](size_t bytes) -> char* {
    char* p = ws + off;
    off = (off + bytes + 255) & ~(size_t)255;
    return p;
  };
  float* dinv = (float*)take((size_t)NB * 4);
  int* cnt = (int*)take((size_t)NB * 4);
  int* starts = (int*)take((size_t)NB * 4);
  int* bsum = (int*)take((size_t)SCAN_NBLK * 4);
  int* esrc = (int*)take((size_t)NE * 4);
  float* stats1 = (float*)take((size_t)NREP * 2 * C1 * 4);
  float* stats2 = (float*)take((size_t)NREP * 2 * C2 * 4);
  float* sc1 = (float*)take(C1 * 4);
  float* sh1 = (float*)take(C1 * 4);
  float* sc2 = (float*)take(C2 * 4);
  float* sh2 = (float*)take(C2 * 4);
  float* counts = (float*)take((size_t)NG * 4);
  float* pooled = (float*)take((size_t)NG * C2 * 4);
  unsigned short* Wtf1 = (unsigned short*)take((size_t)4 * C0 * C1 * 2);
  unsigned short* Wtf2 = (unsigned short*)take((size_t)4 * C1 * C2 * 2);
  unsigned short* out1 = (unsigned short*)take((size_t)NN * C1 * 2);
  const size_t min_agg = (size_t)3 * 128 * C1 * 2;
  if (off + min_agg > ws_size) {
    k_fill<<<(out_size + 255) / 256, 256, 0, stream>>>(outp, out_size, 100.f);
    return;
  }
  unsigned short* aggXb = (unsigned short*)(ws + off);
  const size_t left = ws_size - off;
  long long ch1 = (long long)(left / ((size_t)3 * C0 * 2)) & ~127LL;
  long long ch2 = (long long)(left / ((size_t)3 * C1 * 2)) & ~127LL;
  if (ch1 > NN) ch1 = NN;
  if (ch2 > NN) ch2 = NN;

  dim3 blk(256);
  hipMemsetAsync(cnt, 0, (size_t)NB * 4, stream);
  hipMemsetAsync(stats1, 0, (size_t)NREP * 2 * C1 * 4, stream);
  hipMemsetAsync(stats2, 0, (size_t)NREP * 2 * C2 * 4, stream);
  hipMemsetAsync(counts, 0, (size_t)NG * 4, stream);
  hipMemsetAsync(pooled, 0, (size_t)NG * C2 * 4, stream);

  // ---- CSR build (histogram doubles as degree) ----
  k_hist<<<(NE + 255) / 256, blk, 0, stream>>>(dstI, et, cnt);
  k_dinvI<<<(NB + 255) / 256, blk, 0, stream>>>(cnt, dinv);
  k_counts<<<(NN + 255) / 256, blk, 0, stream>>>(batch, counts);
  k_scan1<<<SCAN_NBLK, blk, 0, stream>>>(cnt, starts, bsum);
  k_scan2<<<1, 64, 0, stream>>>(bsum);
  k_scan3<<<(NB + 255) / 256, blk, 0, stream>>>(starts, bsum);
  k_place<<<(NE + 255) / 256, blk, 0, stream>>>(srcI, dstI, et, starts, esrc);

  k_prepw<<<(4 * C0 * C1 + 255) / 256, blk, 0, stream>>>(Wid0, Wc0, Wtf1, C0, C1);
  k_prepw<<<(4 * C1 * C2 + 255) / 256, blk, 0, stream>>>(Wid1, Wc1, Wtf2, C1, C2);

  // ---- layer 1: x (f32, 32ch) -> out1 bf16 pre-BN (128ch, permuted) + stats1 ----
  for (long long lo = 0; lo < NN; lo += ch1) {
    const int nloc = (int)((NN - lo < ch1) ? (NN - lo) : ch1);
    k_agg<C0, float><<<(3 * nloc * 32 + 255) / 256, blk, 0, stream>>>(starts, esrc, dinv, x, aggXb,
                                                                      (int)lo, nloc);
    k_fin<C0, C1, 32, false, true, false><<<8 * 2 * 32, 512, 0, stream>>>(
        x, aggXb, (int)lo, nloc, Wtf1, bid0, bc0, out1, stats1, nullptr, nullptr);
  }
  k_bnfin<<<1, blk, 0, stream>>>(stats1, gm0, bt0, sc1, sh1, C1);
  k_bnfold<<<(int)(((size_t)NN * C1 / 8 + 255) / 256), blk, 0, stream>>>(out1, sc1, sh1);

  // ---- layer 2: out1 bf16 (BN1 folded, permuted) -> stats2 + pre-BN pooled ----
  for (long long lo = 0; lo < NN; lo += ch2) {
    const int nloc = (int)((NN - lo < ch2) ? (NN - lo) : ch2);
    k_agg<C1, unsigned short><<<(3 * nloc * 64 + 255) / 256, blk, 0, stream>>>(starts, esrc, dinv, out1,
                                                                               aggXb, (int)lo, nloc);
    k_fin<C1, C2, 16, true, false, true><<<8 * 4 * 16, 512, 0, stream>>>(
        out1, aggXb, (int)lo, nloc, Wtf2, bid1, bc1, nullptr, stats2, pooled, batch);
  }
  k_bnfin<<<1, blk, 0, stream>>>(stats2, gm1, bt1, sc2, sh2, C2);

  // ---- MLP head ----
  k_mlp<<<NG, blk, 0, stream>>>(pooled, counts, sc2, sh2, Wf1, bf1, Wf2, bf2, outp);
}

// Round 12
// 612.195 us; speedup vs baseline: 2.2365x; 2.2365x over previous
//
#include <hip/hip_runtime.h>
#include <cstdint>
#include <cstddef>

#define NN 200000
#define NE 600000
#define NG 8192
#define C0 32
#define C1 128
#define C2 256
#define MLPH 256
#define NCLS 10
#define NB (3 * NN)
#define SCAN_BPB 1024
#define SCAN_NBLK ((NB + SCAN_BPB - 1) / SCAN_BPB)
#define NREP 8  // stats atomic replication

typedef __attribute__((ext_vector_type(8))) short short8b;  // 8 bf16 = 4 VGPR
typedef __attribute__((ext_vector_type(4))) float f32x4;

__device__ __forceinline__ void atomAddF(float* p, float v) { unsafeAtomicAdd(p, v); }

__device__ __forceinline__ float b2f(unsigned short u) {
  union { unsigned u; float f; } v; v.u = ((unsigned)u) << 16; return v.f;
}
__device__ __forceinline__ unsigned short f2b(float f) {  // RNE
  union { float f; unsigned u; } v; v.f = f;
  return (unsigned short)((v.u + 0x7FFF + ((v.u >> 16) & 1)) >> 16);
}

// ---------------- small utility kernels ----------------
__global__ __launch_bounds__(256) void k_fill(float* __restrict__ p, int n, float v) {
  int i = blockIdx.x * 256 + threadIdx.x;
  if (i < n) p[i] = v;
}

__global__ __launch_bounds__(256) void k_counts(const int* __restrict__ batch, float* __restrict__ counts) {
  int n = blockIdx.x * 256 + threadIdx.x;
  if (n < NN) atomAddF(&counts[batch[n]], 1.f);
}

// ---------------- CSR build: histogram (= degree), scan, place ----------------
__global__ __launch_bounds__(256) void k_hist(const int* __restrict__ dst, const int* __restrict__ et,
                                              int* __restrict__ cnt) {
  int e = blockIdx.x * 256 + threadIdx.x;
  if (e < NE) atomicAdd(&cnt[et[e] * NN + dst[e]], 1);
}

__global__ __launch_bounds__(256) void k_dinvI(const int* __restrict__ cnt, float* __restrict__ dinv) {
  int i = blockIdx.x * 256 + threadIdx.x;
  if (i < NB) { int c = cnt[i]; dinv[i] = (c > 0) ? 1.f / sqrtf((float)c) : 0.f; }
}

__global__ __launch_bounds__(256) void k_scan1(const int* __restrict__ cnt, int* __restrict__ starts,
                                               int* __restrict__ bsum) {
  __shared__ int sh[256];
  const int b0 = blockIdx.x * SCAN_BPB + threadIdx.x * 4;
  int v[4]; int tot = 0;
#pragma unroll
  for (int j = 0; j < 4; j++) {
    int b = b0 + j;
    v[j] = tot;
    tot += (b < NB) ? cnt[b] : 0;
  }
  sh[threadIdx.x] = tot;
  __syncthreads();
  for (int ofs = 1; ofs < 256; ofs <<= 1) {
    int add = (threadIdx.x >= ofs) ? sh[threadIdx.x - ofs] : 0;
    __syncthreads();
    sh[threadIdx.x] += add;
    __syncthreads();
  }
  const int excl = (threadIdx.x == 0) ? 0 : sh[threadIdx.x - 1];
#pragma unroll
  for (int j = 0; j < 4; j++) {
    int b = b0 + j;
    if (b < NB) starts[b] = excl + v[j];
  }
  if (threadIdx.x == 255) bsum[blockIdx.x] = sh[255];
}

__global__ void k_scan2(int* __restrict__ bsum) {
  if (threadIdx.x == 0) {
    int acc = 0;
    for (int i = 0; i < SCAN_NBLK; i++) { int t = bsum[i]; bsum[i] = acc; acc += t; }
  }
}

__global__ __launch_bounds__(256) void k_scan3(int* __restrict__ starts, const int* __restrict__ bsum) {
  int b = blockIdx.x * 256 + threadIdx.x;
  if (b < NB) starts[b] += bsum[b / SCAN_BPB];
}

// After k_place, starts[b] == end(b); list for bin b = [b ? starts[b-1] : 0, starts[b])
__global__ __launch_bounds__(256) void k_place(const int* __restrict__ src, const int* __restrict__ dst,
                                               const int* __restrict__ et, int* __restrict__ starts,
                                               int* __restrict__ esrc) {
  int e = blockIdx.x * 256 + threadIdx.x;
  if (e >= NE) return;
  int b = et[e] * NN + dst[e];
  int pos = atomicAdd(&starts[b], 1);
  esrc[pos] = src[e];
}

// ---------------- weight prep: fragment-ordered bf16 ----------------
// [m:4][p:COUT/64][kk:CIN/32][ct:4][l:64][j:8]; ki = kk*32+(l>>4)*4+(j&3)+16*(j>>2), c = p*64+ct*16+(l&15)
__global__ __launch_bounds__(256) void k_prepw(const float* __restrict__ Wid, const float* __restrict__ Wc,
                                               unsigned short* __restrict__ Wtf, int CIN_, int COUT_) {
  int i = blockIdx.x * 256 + threadIdx.x;
  if (i >= 4 * CIN_ * COUT_) return;
  int j = i & 7, lq = (i >> 3) & 63, ct = (i >> 9) & 3;
  int rest = i >> 11;
  int KK = CIN_ / 32, NP = COUT_ / 64;
  int kk = rest % KK; rest /= KK;
  int p = rest % NP; int m = rest / NP;
  int ki = kk * 32 + (lq >> 4) * 4 + (j & 3) + 16 * (j >> 2);
  int c = p * 64 + ct * 16 + (lq & 15);
  float wv = (m == 0) ? Wid[(size_t)ki * COUT_ + c] : Wc[(size_t)((m - 1) * CIN_ + ki) * COUT_ + c];
  Wtf[i] = f2b(wv);
}

// ---------------- gather-reduce aggregation (CSR) ----------------
// aggXb[t*nloc+nl][c] = bf16( dinv_dst * sum_{e in list(t, lo+nl)} dinv_src * h[src][c] )
// Avg bin degree ~1 -> few threads/bin, 16B vector loads.
template <int CIN, typename TIN>
__global__ __launch_bounds__(256) void k_agg(const int* __restrict__ starts, const int* __restrict__ esrc,
                                             const float* __restrict__ dinv, const TIN* __restrict__ h,
                                             unsigned short* __restrict__ aggXb, int lo, int nloc) {
  constexpr int TPB = (CIN == 32) ? 8 : 16;
  constexpr int V = CIN / TPB;  // 4 (f32) or 8 (bf16)
  const int idx = blockIdx.x * 256 + threadIdx.x;
  const int bl = idx / TPB;
  const int lane = idx % TPB;
  if (bl >= 3 * nloc) return;
  const int t = bl / nloc;
  const int bin = t * NN + lo + (bl - t * nloc);
  const int s = (bin == 0) ? 0 : starts[bin - 1];
  const int e2 = starts[bin];
  float acc[V];
#pragma unroll
  for (int j = 0; j < V; j++) acc[j] = 0.f;
  for (int i = s; i < e2; i++) {
    const int sn = esrc[i];
    const float dv = dinv[(size_t)t * NN + sn];
    if (dv == 0.f) continue;
    const TIN* hp = h + (size_t)sn * CIN + lane * V;
    if constexpr (sizeof(TIN) == 2) {
      ushort4 u0 = *(const ushort4*)hp;
      ushort4 u1 = *(const ushort4*)((const unsigned short*)hp + 4);
      acc[0] = fmaf(b2f(u0.x), dv, acc[0]); acc[1] = fmaf(b2f(u0.y), dv, acc[1]);
      acc[2] = fmaf(b2f(u0.z), dv, acc[2]); acc[3] = fmaf(b2f(u0.w), dv, acc[3]);
      if constexpr (V == 8) {
        acc[4] = fmaf(b2f(u1.x), dv, acc[4]); acc[5] = fmaf(b2f(u1.y), dv, acc[5]);
        acc[6] = fmaf(b2f(u1.z), dv, acc[6]); acc[7] = fmaf(b2f(u1.w), dv, acc[7]);
      }
    } else {
      float4 v0 = *(const float4*)hp;
      acc[0] = fmaf(v0.x, dv, acc[0]); acc[1] = fmaf(v0.y, dv, acc[1]);
      acc[2] = fmaf(v0.z, dv, acc[2]); acc[3] = fmaf(v0.w, dv, acc[3]);
    }
  }
  const float dvd = dinv[bin];
  unsigned short* op = aggXb + (size_t)bl * CIN + lane * V;
  ushort4 o0;
  o0.x = f2b(acc[0] * dvd); o0.y = f2b(acc[1] * dvd);
  o0.z = f2b(acc[2] * dvd); o0.w = f2b(acc[3] * dvd);
  *(ushort4*)op = o0;
  if constexpr (V == 8) {
    ushort4 o1;
    o1.x = f2b(acc[4] * dvd); o1.y = f2b(acc[5] * dvd);
    o1.z = f2b(acc[6] * dvd); o1.w = f2b(acc[7] * dvd);
    *(ushort4*)(op + 4) = o1;
  }
}

// ---------------- fused finish via bf16 MFMA, LDS-staged weights, m-pipelined ----------------
// Round-8 structure (per-tile blocks, XCD-swizzled panels) + T14 split stage
// (SLOAD regs early / SWRITE LDS late) + A-fragments prefetched one m ahead.
#define SLOAD(mm)                                                                        \
  {                                                                                      \
    const short8b* g_ = (const short8b*)Wtf + (size_t)((mm) * NP + p) * PMF;             \
    _Pragma("unroll") for (int ii_ = 0; ii_ < KK; ii_++) wreg[ii_] = g_[ii_ * 256 + tid];\
  }

#define SWRITE(mm)                                                                       \
  {                                                                                      \
    short8b* d_ = wlds + ((mm) & 1) * PMF;                                               \
    _Pragma("unroll") for (int ii_ = 0; ii_ < KK; ii_++) d_[ii_ * 256 + tid] = wreg[ii_];\
  }

#define LOADA_M(A0, A1, mm)                                                              \
  {                                                                                      \
    if constexpr ((mm) > 0) {                                                            \
      const unsigned short* ar_ = aggXb + ((size_t)((mm)-1) * nloc + ln0 + rA) * CIN;    \
      _Pragma("unroll") for (int kk_ = 0; kk_ < KK; kk_++) {                             \
        A0[kk_] = *(const ushort4*)(ar_ + kk_ * 32 + lq * 4);                            \
        A1[kk_] = *(const ushort4*)(ar_ + kk_ * 32 + 16 + lq * 4);                       \
      }                                                                                  \
    } else if constexpr (INBF16) {                                                       \
      const unsigned short* xr_ = (const unsigned short*)Xv + (size_t)nA * CIN;          \
      _Pragma("unroll") for (int kk_ = 0; kk_ < KK; kk_++) {                             \
        A0[kk_] = *(const ushort4*)(xr_ + kk_ * 32 + lq * 4);                            \
        A1[kk_] = *(const ushort4*)(xr_ + kk_ * 32 + 16 + lq * 4);                       \
      }                                                                                  \
    } else {                                                                             \
      const float* xr_ = (const float*)Xv + (size_t)nA * CIN;                            \
      _Pragma("unroll") for (int kk_ = 0; kk_ < KK; kk_++) {                             \
        float4 v0_ = *(const float4*)(xr_ + kk_ * 32 + lq * 4);                          \
        float4 v1_ = *(const float4*)(xr_ + kk_ * 32 + 16 + lq * 4);                     \
        A0[kk_] = make_ushort4(f2b(v0_.x), f2b(v0_.y), f2b(v0_.z), f2b(v0_.w));          \
        A1[kk_] = make_ushort4(f2b(v1_.x), f2b(v1_.y), f2b(v1_.z), f2b(v1_.w));          \
      }                                                                                  \
    }                                                                                    \
  }

#define COMPM(A0, A1, mm)                                                                \
  {                                                                                      \
    f32x4 acc_[4];                                                                       \
    _Pragma("unroll") for (int c_ = 0; c_ < 4; c_++) acc_[c_] = (f32x4){0.f, 0.f, 0.f, 0.f}; \
    const short8b* wb_ = wlds + ((mm) & 1) * PMF;                                        \
    _Pragma("unroll") for (int kk_ = 0; kk_ < KK; kk_++) {                               \
      union { ushort4 u4[2]; short8b v; } fa_;                                           \
      fa_.u4[0] = A0[kk_]; fa_.u4[1] = A1[kk_];                                          \
      _Pragma("unroll") for (int c_ = 0; c_ < 4; c_++)                                   \
          acc_[c_] = __builtin_amdgcn_mfma_f32_16x16x32_bf16(                            \
              fa_.v, wb_[kk_ * 256 + c_ * 64 + l], acc_[c_], 0, 0, 0);                   \
    }                                                                                    \
    const float* bp_ = ((mm) == 0) ? bid : bc + (size_t)((mm)-1) * COUT;                 \
    _Pragma("unroll") for (int c_ = 0; c_ < 4; c_++) {                                   \
      float bb_ = bp_[c0 + c_ * 16 + lr];                                                \
      _Pragma("unroll") for (int j_ = 0; j_ < 4; j_++)                                   \
          run[c_][j_] += fmaxf(acc_[c_][j_] + bb_, 0.f);                                 \
    }                                                                                    \
  }

template <int CIN, int COUT, bool INBF16, bool WRITEOUT, bool DOPOOL>
__global__ __launch_bounds__(256, 3) void k_fin(
    const void* __restrict__ Xv, const unsigned short* __restrict__ aggXb,
    int lo, int nloc, int nt, const unsigned short* __restrict__ Wtf,
    const float* __restrict__ bid, const float* __restrict__ bc,
    unsigned short* __restrict__ outb, float* __restrict__ stats,
    float* __restrict__ pooled, const int* __restrict__ batch) {
  constexpr int NP = COUT / 64;
  constexpr int KK = CIN / 32;
  constexpr int PMF = KK * 256;                       // frags per (m,panel) slice
  constexpr int EPI = 64 * 65 * 4 + 2 * 4 * 64 * 4 + 64 * 4;  // tile + sred + sbatch
  constexpr int SMEM_BYTES = (2 * PMF * 16 > EPI) ? 2 * PMF * 16 : EPI;
  __shared__ __align__(16) char smem[SMEM_BYTES];
  short8b* wlds = (short8b*)smem;                     // [2][PMF]
  float (*tile)[65] = (float(*)[65])smem;             // epilogue aliases
  float* sred = (float*)(smem + 64 * 65 * 4);         // [2][4][64]
  int* sbatch = (int*)(smem + 64 * 65 * 4 + 2 * 4 * 64 * 4);

  // ---- XCD swizzle decode: i = xr8 + 8*(ti*NP + p) ----
  const int i = blockIdx.x;
  const int xr8 = i & 7;
  const int xq = i >> 3;
  const int p = xq % NP;
  const int ti = xq / NP;
  const int tileIdx = ti * 8 + xr8;
  if (tileIdx >= nt) return;
  const int ln0 = tileIdx * 64;
  const int n0 = lo + ln0;
  const int c0 = p * 64;
  const int tid = threadIdx.x, w = tid >> 6, l = tid & 63, lr = l & 15, lq = l >> 4;
  const int rA = w * 16 + lr;
  const int nA = n0 + rA;

  f32x4 run[4];
#pragma unroll
  for (int ct = 0; ct < 4; ct++) run[ct] = (f32x4){0.f, 0.f, 0.f, 0.f};

  short8b wreg[KK];
  ushort4 a0A[KK], a1A[KK], a0B[KK], a1B[KK];

  // ---- prologue: stage m0 weights + load A(0); both in flight together ----
  SLOAD(0)
  LOADA_M(a0A, a1A, 0)
  SWRITE(0)
  __syncthreads();
  // ---- m=0 ----
  SLOAD(1)
  LOADA_M(a0B, a1B, 1)
  COMPM(a0A, a1A, 0)
  SWRITE(1)
  __syncthreads();
  // ---- m=1 ----
  SLOAD(2)
  LOADA_M(a0A, a1A, 2)
  COMPM(a0B, a1B, 1)
  SWRITE(2)
  __syncthreads();
  // ---- m=2 ----
  SLOAD(3)
  LOADA_M(a0B, a1B, 3)
  COMPM(a0A, a1A, 2)
  SWRITE(3)
  __syncthreads();
  // ---- m=3 ----
  COMPM(a0B, a1B, 3)
  __syncthreads();  // all waves done reading wlds before epilogue aliases it

  // ---- epilogue (smem aliased as tile/sred/sbatch) ----
#pragma unroll
  for (int ct = 0; ct < 4; ct++)
#pragma unroll
    for (int j = 0; j < 4; j++) tile[w * 16 + lq * 4 + j][ct * 16 + lr] = run[ct][j];
  if (DOPOOL && tid < 64) sbatch[tid] = batch[n0 + tid];
  __syncthreads();

  if (WRITEOUT) {
    const int r = tid >> 2, cg = (tid & 3) * 16;
    ushort4 o[4];
#pragma unroll
    for (int g4 = 0; g4 < 4; g4++) {
      o[g4].x = f2b(tile[r][cg + g4 * 4 + 0]);
      o[g4].y = f2b(tile[r][cg + g4 * 4 + 1]);
      o[g4].z = f2b(tile[r][cg + g4 * 4 + 2]);
      o[g4].w = f2b(tile[r][cg + g4 * 4 + 3]);
    }
    ushort4* dst4 = (ushort4*)(outb + (size_t)(n0 + r) * COUT + c0 + cg);
#pragma unroll
    for (int g4 = 0; g4 < 4; g4++) dst4[g4] = o[g4];
  }
  {  // parallel stats + pool: thread = (rowgroup rg, col)
    const int col = tid & 63, rg = tid >> 6, r0 = rg * 16;
    float s = 0.f, ss = 0.f, gs = 0.f;
    int curg = DOPOOL ? sbatch[r0] : 0;
#pragma unroll
    for (int r = 0; r < 16; r++) {
      float v = tile[r0 + r][col];
      s += v; ss += v * v;
      if (DOPOOL) {
        int g = sbatch[r0 + r];
        if (g != curg) { atomAddF(&pooled[(size_t)curg * C2 + c0 + col], gs); gs = 0.f; curg = g; }
        gs += v;
      }
    }
    if (DOPOOL) atomAddF(&pooled[(size_t)curg * C2 + c0 + col], gs);
    sred[0 * 4 * 64 + rg * 64 + col] = s;
    sred[1 * 4 * 64 + rg * 64 + col] = ss;
  }
  __syncthreads();
  if (tid < 64) {
    float s4 = sred[0 + tid] + sred[64 + tid] + sred[128 + tid] + sred[192 + tid];
    float ss4 = sred[256 + tid] + sred[320 + tid] + sred[384 + tid] + sred[448 + tid];
    float* st = stats + (size_t)(tileIdx & (NREP - 1)) * 2 * COUT;
    atomAddF(&st[c0 + tid], s4);
    atomAddF(&st[COUT + c0 + tid], ss4);
  }
}

// ---------------- BN finalize (sums NREP replicas) -> per-channel scale/shift ----------------
__global__ __launch_bounds__(256) void k_bnfin(const float* __restrict__ stats, const float* __restrict__ gamma,
                                               const float* __restrict__ beta, float* __restrict__ sc,
                                               float* __restrict__ sh, int COUT) {
  int c = threadIdx.x;
  if (c < COUT) {
    float su = 0.f, ssu = 0.f;
    for (int r = 0; r < NREP; r++) {
      su += stats[(size_t)r * 2 * COUT + c];
      ssu += stats[(size_t)r * 2 * COUT + COUT + c];
    }
    const float invN = 1.f / (float)NN;
    float m = su * invN;
    float v = ssu * invN - m * m;
    float s = gamma[c] / sqrtf(v + 1e-5f);
    sc[c] = s;
    sh[c] = fmaf(-m, s, beta[c]);
  }
}

// ---------------- fold BN1 into out1 (bf16, in place) ----------------
__global__ __launch_bounds__(256) void k_bnfold(unsigned short* __restrict__ o, const float* __restrict__ sc,
                                                const float* __restrict__ sh) {
  size_t i8 = ((size_t)blockIdx.x * 256 + threadIdx.x) * 8;
  if (i8 >= (size_t)NN * C1) return;
  const int c = (int)(i8 & (C1 - 1));
  ushort4 a = *(ushort4*)(o + i8);
  ushort4 b = *(ushort4*)(o + i8 + 4);
  a.x = f2b(fmaf(b2f(a.x), sc[c + 0], sh[c + 0]));
  a.y = f2b(fmaf(b2f(a.y), sc[c + 1], sh[c + 1]));
  a.z = f2b(fmaf(b2f(a.z), sc[c + 2], sh[c + 2]));
  a.w = f2b(fmaf(b2f(a.w), sc[c + 3], sh[c + 3]));
  b.x = f2b(fmaf(b2f(b.x), sc[c + 4], sh[c + 4]));
  b.y = f2b(fmaf(b2f(b.y), sc[c + 5], sh[c + 5]));
  b.z = f2b(fmaf(b2f(b.z), sc[c + 6], sh[c + 6]));
  b.w = f2b(fmaf(b2f(b.w), sc[c + 7], sh[c + 7]));
  *(ushort4*)(o + i8) = a;
  *(ushort4*)(o + i8 + 4) = b;
}

// ---------------- MLP head: BN2 affine folded into pooled sums ----------------
__global__ __launch_bounds__(256) void k_mlp(const float* __restrict__ pooled, const float* __restrict__ counts,
                                             const float* __restrict__ sc2, const float* __restrict__ sh2,
                                             const float* __restrict__ Wf1, const float* __restrict__ bf1,
                                             const float* __restrict__ Wf2, const float* __restrict__ bf2,
                                             float* __restrict__ out) {
  __shared__ float feat[257];
  __shared__ float hid[256];
  const int g = blockIdx.x, t = threadIdx.x;
  const float cnt = counts[g];
  feat[t] = fmaf(sc2[t], pooled[(size_t)g * C2 + t], sh2[t] * cnt);
  if (t == 0) feat[256] = cnt * 0.025f;
  __syncthreads();
  float acc = bf1[t];
  for (int i = 0; i < 257; i++) acc = fmaf(feat[i], Wf1[(size_t)i * MLPH + t], acc);
  hid[t] = fmaxf(acc, 0.f);
  __syncthreads();
  if (t < NCLS) {
    float o = bf2[t];
    for (int j = 0; j < MLPH; j++) o = fmaf(hid[j], Wf2[(size_t)j * NCLS + t], o);
    out[(size_t)g * NCLS + t] = o;
  }
}

extern "C" void kernel_launch(void* const* d_in, const int* in_sizes, int n_in,
                              void* d_out, int out_size, void* d_ws, size_t ws_size,
                              hipStream_t stream) {
  const float* x = (const float*)d_in[0];
  const int* ei = (const int*)d_in[1];
  const int* et = (const int*)d_in[2];
  const int* batch = (const int*)d_in[3];
  const float* Wc0 = (const float*)d_in[4];
  const float* bc0 = (const float*)d_in[5];
  const float* Wid0 = (const float*)d_in[6];
  const float* bid0 = (const float*)d_in[7];
  const float* gm0 = (const float*)d_in[8];
  const float* bt0 = (const float*)d_in[9];
  const float* Wc1 = (const float*)d_in[10];
  const float* bc1 = (const float*)d_in[11];
  const float* Wid1 = (const float*)d_in[12];
  const float* bid1 = (const float*)d_in[13];
  const float* gm1 = (const float*)d_in[14];
  const float* bt1 = (const float*)d_in[15];
  const float* Wf1 = (const float*)d_in[16];
  const float* bf1 = (const float*)d_in[17];
  const float* Wf2 = (const float*)d_in[18];
  const float* bf2 = (const float*)d_in[19];
  const int* srcI = ei;
  const int* dstI = ei + NE;
  float* outp = (float*)d_out;

  char* ws = (char*)d_ws;
  size_t off = 0;
  auto take = [&](size_t bytes) -> char* {
    char* p = ws + off;
    off = (off + bytes + 255) & ~(size_t)255;
    return p;
  };
  float* dinv = (float*)take((size_t)NB * 4);
  int* cnt = (int*)take((size_t)NB * 4);
  int* starts = (int*)take((size_t)NB * 4);
  int* bsum = (int*)take((size_t)SCAN_NBLK * 4);
  int* esrc = (int*)take((size_t)NE * 4);
  float* stats1 = (float*)take((size_t)NREP * 2 * C1 * 4);
  float* stats2 = (float*)take((size_t)NREP * 2 * C2 * 4);
  float* sc1 = (float*)take(C1 * 4);
  float* sh1 = (float*)take(C1 * 4);
  float* sc2 = (float*)take(C2 * 4);
  float* sh2 = (float*)take(C2 * 4);
  float* counts = (float*)take((size_t)NG * 4);
  float* pooled = (float*)take((size_t)NG * C2 * 4);
  unsigned short* Wtf1 = (unsigned short*)take((size_t)4 * C0 * C1 * 2);
  unsigned short* Wtf2 = (unsigned short*)take((size_t)4 * C1 * C2 * 2);
  unsigned short* out1 = (unsigned short*)take((size_t)NN * C1 * 2);
  const size_t min_agg = (size_t)3 * 64 * C1 * 2;
  if (off + min_agg > ws_size) {
    k_fill<<<(out_size + 255) / 256, 256, 0, stream>>>(outp, out_size, 100.f);
    return;
  }
  unsigned short* aggXb = (unsigned short*)(ws + off);
  const size_t left = ws_size - off;
  long long ch1 = (long long)(left / ((size_t)3 * C0 * 2)) & ~63LL;
  long long ch2 = (long long)(left / ((size_t)3 * C1 * 2)) & ~63LL;
  if (ch1 > NN) ch1 = NN;
  if (ch2 > NN) ch2 = NN;

  dim3 blk(256);
  hipMemsetAsync(cnt, 0, (size_t)NB * 4, stream);
  hipMemsetAsync(stats1, 0, (size_t)NREP * 2 * C1 * 4, stream);
  hipMemsetAsync(stats2, 0, (size_t)NREP * 2 * C2 * 4, stream);
  hipMemsetAsync(counts, 0, (size_t)NG * 4, stream);
  hipMemsetAsync(pooled, 0, (size_t)NG * C2 * 4, stream);

  // ---- CSR build (histogram doubles as degree) ----
  k_hist<<<(NE + 255) / 256, blk, 0, stream>>>(dstI, et, cnt);
  k_dinvI<<<(NB + 255) / 256, blk, 0, stream>>>(cnt, dinv);
  k_counts<<<(NN + 255) / 256, blk, 0, stream>>>(batch, counts);
  k_scan1<<<SCAN_NBLK, blk, 0, stream>>>(cnt, starts, bsum);
  k_scan2<<<1, 64, 0, stream>>>(bsum);
  k_scan3<<<(NB + 255) / 256, blk, 0, stream>>>(starts, bsum);
  k_place<<<(NE + 255) / 256, blk, 0, stream>>>(srcI, dstI, et, starts, esrc);

  k_prepw<<<(4 * C0 * C1 + 255) / 256, blk, 0, stream>>>(Wid0, Wc0, Wtf1, C0, C1);
  k_prepw<<<(4 * C1 * C2 + 255) / 256, blk, 0, stream>>>(Wid1, Wc1, Wtf2, C1, C2);

  // ---- layer 1: x (f32, 32ch) -> out1 bf16 pre-BN (128ch) + stats1 ----
  for (long long lo = 0; lo < NN; lo += ch1) {
    const int nloc = (int)((NN - lo < ch1) ? (NN - lo) : ch1);
    const int nt = nloc / 64;
    const int nt8 = (nt + 7) & ~7;
    k_agg<C0, float><<<(3 * nloc * 8 + 255) / 256, blk, 0, stream>>>(starts, esrc, dinv, x, aggXb,
                                                                     (int)lo, nloc);
    k_fin<C0, C1, false, true, false><<<nt8 * (C1 / 64), blk, 0, stream>>>(
        x, aggXb, (int)lo, nloc, nt, Wtf1, bid0, bc0, out1, stats1, nullptr, nullptr);
  }
  k_bnfin<<<1, blk, 0, stream>>>(stats1, gm0, bt0, sc1, sh1, C1);
  k_bnfold<<<(int)(((size_t)NN * C1 / 8 + 255) / 256), blk, 0, stream>>>(out1, sc1, sh1);

  // ---- layer 2: out1 bf16 (BN1 folded) -> stats2 + pre-BN pooled ----
  for (long long lo = 0; lo < NN; lo += ch2) {
    const int nloc = (int)((NN - lo < ch2) ? (NN - lo) : ch2);
    const int nt = nloc / 64;
    const int nt8 = (nt + 7) & ~7;
    k_agg<C1, unsigned short><<<(3 * nloc * 16 + 255) / 256, blk, 0, stream>>>(starts, esrc, dinv, out1,
                                                                               aggXb, (int)lo, nloc);
    k_fin<C1, C2, true, false, true><<<nt8 * (C2 / 64), blk, 0, stream>>>(
        out1, aggXb, (int)lo, nloc, nt, Wtf2, bid1, bc1, nullptr, stats2, pooled, batch);
  }
  k_bnfin<<<1, blk, 0, stream>>>(stats2, gm1, bt1, sc2, sh2, C2);

  // ---- MLP head ----
  k_mlp<<<NG, blk, 0, stream>>>(pooled, counts, sc2, sh2, Wf1, bf1, Wf2, bf2, outp);
}